// Round 8
// baseline (2586.117 us; speedup 1.0000x reference)
//
#include <hip/hip_runtime.h>
#include <stdint.h>

typedef unsigned short u16;
typedef uint32_t u32;
typedef __attribute__((ext_vector_type(4))) u32 u32x4;
typedef __attribute__((ext_vector_type(8))) short v8s;
typedef __attribute__((ext_vector_type(4))) float f32x4;

// ---------------- workspace layout (bytes) ----------------
// h      : u32 [2 buf][4 grp][16 row][512 hid]  @ 0         (262144)
//          word = (bf16_hi<<16)|(bf16_lo&0xFFFE)|tag, tag=(t>>1)&1
// whh_hi : u16 [64 w][2 nt][16 c][64 lane][8]   @ 262144    (2 MiB)
// whh_lo : same                                 @ 2359296   (2 MiB)
// wih_hi : u16 [64 w][2 nt][8 e][64 lane][8]    @ 4456448   (1 MiB)
#define OFF_H      0
#define OFF_WHH_HI 262144
#define OFF_WHH_LO 2359296
#define OFF_WIH    4456448

__device__ __forceinline__ u16 bf_hi(float v) {
  return (u16)(__builtin_bit_cast(u32, v) >> 16);
}
__device__ __forceinline__ float bf_up(u16 h) {
  return __builtin_bit_cast(float, (u32)h << 16);
}
__device__ __forceinline__ float tanhf_fast(float x) {
  float e = __expf(2.f * x);
  return 1.f - 2.f / (e + 1.f);
}
__device__ __forceinline__ float sigm(float x) {
  return 1.f / (1.f + __expf(-x));
}
// v_perm_b32 packers: pkhi(a,b) = (b&0xffff0000)|(a>>16); pklo = (b<<16)|(a&0xffff)
__device__ __forceinline__ u32 pkhi(u32 a, u32 b) { return __builtin_amdgcn_perm(b, a, 0x07060302u); }
__device__ __forceinline__ u32 pklo(u32 a, u32 b) { return __builtin_amdgcn_perm(b, a, 0x05040100u); }

// ---------------- init: buf0 = 0 (h0 valid, tag 0), buf1 = 1 (invalid at t=1)
__global__ void k_init(u32* h) {
  int i = blockIdx.x * 256 + threadIdx.x;   // 65536 words
  if (i < 65536) h[i] = (i < 32768) ? 0u : 1u;
}

// ---------------- pre-pack weights into per-octet MFMA fragment planes -------
// col map: n32 = nt*16 + (lane&15); R = (n32>>3)*512 + w*8 + (n32&7); k = c*32+8*(lane>>4)+i
__global__ void k_prep(const float* __restrict__ Wih, const float* __restrict__ Whh,
                       uint8_t* __restrict__ ws) {
  int idx = blockIdx.x * 256 + threadIdx.x;   // 196608 total
  if (idx < 131072) {                          // W_hh hi+lo
    int lane = idx & 63;
    int c  = (idx >> 6) & 15;
    int nt = (idx >> 10) & 1;
    int w  = idx >> 11;
    int n32 = nt * 16 + (lane & 15);
    int R = (n32 >> 3) * 512 + w * 8 + (n32 & 7);
    int gq = lane >> 4;
    const float* src = Whh + (size_t)R * 512 + c * 32 + 8 * gq;
    u16* dh = (u16*)(ws + OFF_WHH_HI) + (size_t)idx * 8;
    u16* dl = (u16*)(ws + OFF_WHH_LO) + (size_t)idx * 8;
#pragma unroll
    for (int i = 0; i < 8; ++i) {
      float v = src[i];
      u16 hi = bf_hi(v);
      dh[i] = hi;
      dl[i] = bf_hi(v - bf_up(hi));
    }
  } else {                                     // W_ih hi only
    int fidx = idx - 131072;
    if (fidx >= 65536) return;
    int lane = fidx & 63;
    int e  = (fidx >> 6) & 7;
    int nt = (fidx >> 9) & 1;
    int w  = fidx >> 10;
    int n32 = nt * 16 + (lane & 15);
    int R = (n32 >> 3) * 512 + w * 8 + (n32 & 7);
    int gq = lane >> 4;
    const float* src = Wih + (size_t)R * 256 + e * 32 + 8 * gq;
    u16* dh = (u16*)(ws + OFF_WIH) + (size_t)fidx * 8;
#pragma unroll
    for (int i = 0; i < 8; ++i) dh[i] = bf_hi(src[i]);
  }
}

// ---------------- asm helpers ----------------
#define LOADC(DST, PTR) \
  asm volatile("global_load_dwordx4 %0, %1, off sc0 sc1" : "=v"(DST) : "v"(PTR))
#define STORED(PTR, VAL) \
  asm volatile("global_store_dword %0, %1, off sc0 sc1" :: "v"(PTR), "v"(VAL) : "memory")

#define WAITV_(N) { asm volatile("s_waitcnt vmcnt(" #N ")" ::: "memory"); \
                    __builtin_amdgcn_sched_barrier(0); }
#define WAITV(N) WAITV_(N)

#define MFMA16(a, b, c) __builtin_amdgcn_mfma_f32_16x16x32_bf16((a), (b), (c), 0, 0, 0)
#define BC(x) __builtin_bit_cast(v8s, x)

// two f32x4 -> (hi,lo) bf16 fragments via v_perm packing
#define CVTPAIR(F0, F1, AH, AL) { \
  u32 u0_=__builtin_bit_cast(u32,(F0)[0]), u1_=__builtin_bit_cast(u32,(F0)[1]); \
  u32 u2_=__builtin_bit_cast(u32,(F0)[2]), u3_=__builtin_bit_cast(u32,(F0)[3]); \
  u32 u4_=__builtin_bit_cast(u32,(F1)[0]), u5_=__builtin_bit_cast(u32,(F1)[1]); \
  u32 u6_=__builtin_bit_cast(u32,(F1)[2]), u7_=__builtin_bit_cast(u32,(F1)[3]); \
  float l0_=(F0)[0]-__builtin_bit_cast(float,u0_&0xffff0000u); \
  float l1_=(F0)[1]-__builtin_bit_cast(float,u1_&0xffff0000u); \
  float l2_=(F0)[2]-__builtin_bit_cast(float,u2_&0xffff0000u); \
  float l3_=(F0)[3]-__builtin_bit_cast(float,u3_&0xffff0000u); \
  float l4_=(F1)[0]-__builtin_bit_cast(float,u4_&0xffff0000u); \
  float l5_=(F1)[1]-__builtin_bit_cast(float,u5_&0xffff0000u); \
  float l6_=(F1)[2]-__builtin_bit_cast(float,u6_&0xffff0000u); \
  float l7_=(F1)[3]-__builtin_bit_cast(float,u7_&0xffff0000u); \
  u32x4 hw_, lw_; \
  hw_[0]=pkhi(u0_,u1_); hw_[1]=pkhi(u2_,u3_); hw_[2]=pkhi(u4_,u5_); hw_[3]=pkhi(u6_,u7_); \
  lw_[0]=pkhi(__builtin_bit_cast(u32,l0_),__builtin_bit_cast(u32,l1_)); \
  lw_[1]=pkhi(__builtin_bit_cast(u32,l2_),__builtin_bit_cast(u32,l3_)); \
  lw_[2]=pkhi(__builtin_bit_cast(u32,l4_),__builtin_bit_cast(u32,l5_)); \
  lw_[3]=pkhi(__builtin_bit_cast(u32,l6_),__builtin_bit_cast(u32,l7_)); \
  (AH)=BC(hw_); (AL)=BC(lw_); }

// tag check of slot s: all 8 LSBs == texp (texp wave-uniform)
#define TAGOK(s) (__all(texp ? \
  (((HA[2*(s)][0]&HA[2*(s)][1]&HA[2*(s)][2]&HA[2*(s)][3] \
    &HA[2*(s)+1][0]&HA[2*(s)+1][1]&HA[2*(s)+1][2]&HA[2*(s)+1][3])&1u)==1u) : \
  (((HA[2*(s)][0]|HA[2*(s)][1]|HA[2*(s)][2]|HA[2*(s)][3] \
    |HA[2*(s)+1][0]|HA[2*(s)+1][1]|HA[2*(s)+1][2]|HA[2*(s)+1][3])&1u)==0u)))

// consume chunk c from slot s: perm-unpack + 2x(2 LDS B-frags + 3 MFMAs)
#define CONSC(c, s) { \
  u32x4 w0_ = HA[2*(s)], w1_ = HA[2*(s)+1]; \
  u32x4 hiw_, low_; \
  hiw_[0]=pkhi(w0_[0],w0_[1]); hiw_[1]=pkhi(w0_[2],w0_[3]); \
  hiw_[2]=pkhi(w1_[0],w1_[1]); hiw_[3]=pkhi(w1_[2],w1_[3]); \
  low_[0]=pklo(w0_[0],w0_[1]); low_[1]=pklo(w0_[2],w0_[3]); \
  low_[2]=pklo(w1_[0],w1_[1]); low_[3]=pklo(w1_[2],w1_[3]); \
  v8s ah_=BC(hiw_), al_=BC(low_); \
  f32x4* acx_ = ((c)&1) ? accO : accE; \
  { v8s bh_=BC(*(const u32x4*)&ldsW[(((c))*64+lane)*8]); \
    v8s bl_=BC(*(const u32x4*)&ldsW[16384+(((c))*64+lane)*8]); \
    acx_[0]=MFMA16(ah_,bh_,acx_[0]); acx_[0]=MFMA16(ah_,bl_,acx_[0]); acx_[0]=MFMA16(al_,bh_,acx_[0]); } \
  { v8s bh2_=BC(*(const u32x4*)&ldsW[((16+(c))*64+lane)*8]); \
    v8s bl2_=BC(*(const u32x4*)&ldsW[16384+((16+(c))*64+lane)*8]); \
    acx_[1]=MFMA16(ah_,bh2_,acx_[1]); acx_[1]=MFMA16(ah_,bl2_,acx_[1]); acx_[1]=MFMA16(al_,bh2_,acx_[1]); } }

#define ISSUEC(c, s) { LOADC(HA[2*(s)], hb + (c)*32); LOADC(HA[2*(s)+1], hb + (c)*32 + 4); }
#define RISS(c)  if (pend & (1u<<(c))) ISSUEC(c, (c)&7)
#define RCON(c)  if (pend & (1u<<(c))) { if (TAGOK((c)&7)) { CONSC(c, (c)&7); pend &= ~(1u<<(c)); } }

// ---------------- persistent recurrence kernel ----------------
// Grid 256 x 64 thr: wave = (group g = bid>>6, hid octet w = bid&63).
// Full-K per wave: no k-split, no reduce, no barriers. h exchange: tagged dwords.
__global__ __launch_bounds__(64, 1) void k_lstm(
    const int* __restrict__ xin, const float* __restrict__ emb,
    const float* __restrict__ bih, const float* __restrict__ bhh,
    uint8_t* __restrict__ ws, float* __restrict__ dout)
{
  const int bid = blockIdx.x;
  const int w = bid & 63;
  const int g = bid >> 6;
  const int lane = threadIdx.x;
  const int cl = lane & 15;
  const int gq = lane >> 4;

  u32* hbuf = (u32*)(ws + OFF_H);

  __shared__ u16 ldsW[32768];   // 64 KiB: [0,16384) = W_hh hi, [16384,32768) = lo

  // LDS fill: this octet's W_hh fragment planes (single wave: no barrier needed)
  {
    const u16* gh = (const u16*)(ws + OFF_WHH_HI) + (size_t)w * 16384;
    const u16* gl = (const u16*)(ws + OFF_WHH_LO) + (size_t)w * 16384;
#pragma unroll 4
    for (int q = 0; q < 32; ++q) {
      *(u32x4*)&ldsW[(q * 64 + lane) * 8]         = *(const u32x4*)&gh[(q * 64 + lane) * 8];
      *(u32x4*)&ldsW[16384 + (q * 64 + lane) * 8] = *(const u32x4*)&gl[(q * 64 + lane) * 8];
    }
  }

  // W_ih hi fragments resident in VGPRs/AGPRs (compiler-managed)
  u32x4 WIH[2][8];
  {
    const u16* gi = (const u16*)(ws + OFF_WIH);
#pragma unroll
    for (int nt = 0; nt < 2; ++nt)
#pragma unroll
      for (int e = 0; e < 8; ++e)
        WIH[nt][e] = *(const u32x4*)&gi[(((size_t)(w * 2 + nt) * 8 + e) * 64 + lane) * 8];
  }

  float bias[2];
#pragma unroll
  for (int nt = 0; nt < 2; ++nt) {
    int n32 = nt * 16 + cl;
    int R = (n32 >> 3) * 512 + w * 8 + (n32 & 7);
    bias[nt] = bih[R] + bhh[R];
  }

  const int brow = g * 16 + cl;
  f32x4 EA[16];
  {
    const float* eb = emb + (size_t)xin[brow * 512] * 256;
#pragma unroll
    for (int e = 0; e < 8; ++e) {
      EA[2*e]   = *(const f32x4*)(eb + e * 32 + 8 * gq);
      EA[2*e+1] = *(const f32x4*)(eb + e * 32 + 8 * gq + 4);
    }
  }

  float cst[4] = {0.f, 0.f, 0.f, 0.f};

  for (int t = 0; t < 512; ++t) {
    // ---- phase 1: emb projection (independent of h; EA prefetched) ----
    f32x4 accE[2] = {}, accO[2] = {};
#pragma unroll
    for (int e = 0; e < 8; ++e) {
      v8s ah_, al_;
      CVTPAIR(EA[2*e], EA[2*e+1], ah_, al_);
      f32x4* acx = (e & 1) ? accO : accE;
      v8s b0 = BC(WIH[0][e]), b1 = BC(WIH[1][e]);
      acx[0] = MFMA16(ah_, b0, acx[0]);
      acx[0] = MFMA16(al_, b0, acx[0]);
      acx[1] = MFMA16(ah_, b1, acx[1]);
      acx[1] = MFMA16(al_, b1, acx[1]);
    }

    const int tok = xin[brow * 512 + ((t + 1) & 511)];

    const u32* hc = hbuf + ((size_t)(t & 1) * 4 + g) * 8192;
    u32* hn = hbuf + ((size_t)((t + 1) & 1) * 4 + g) * 8192;
    const u32 texp = (u32)((t >> 1) & 1);
    const u32* hb = hc + cl * 512 + 8 * gq;

    // ---- 16-chunk tagged ring: counted vmcnt sliding window ----
    u32x4 HA[16];
    u32 pend = 0;
    ISSUEC(0,0); ISSUEC(1,1); ISSUEC(2,2); ISSUEC(3,3);
    ISSUEC(4,4); ISSUEC(5,5); ISSUEC(6,6); ISSUEC(7,7);
    __builtin_amdgcn_sched_barrier(0);
    WAITV(14); if (TAGOK(0)) { CONSC(0,0); } else pend |= 1u<<0;  ISSUEC(8,0);
    WAITV(14); if (TAGOK(1)) { CONSC(1,1); } else pend |= 1u<<1;  ISSUEC(9,1);
    WAITV(14); if (TAGOK(2)) { CONSC(2,2); } else pend |= 1u<<2;  ISSUEC(10,2);
    WAITV(14); if (TAGOK(3)) { CONSC(3,3); } else pend |= 1u<<3;  ISSUEC(11,3);
    WAITV(14); if (TAGOK(4)) { CONSC(4,4); } else pend |= 1u<<4;  ISSUEC(12,4);
    WAITV(14); if (TAGOK(5)) { CONSC(5,5); } else pend |= 1u<<5;  ISSUEC(13,5);
    WAITV(14); if (TAGOK(6)) { CONSC(6,6); } else pend |= 1u<<6;  ISSUEC(14,6);
    WAITV(14); if (TAGOK(7)) { CONSC(7,7); } else pend |= 1u<<7;  ISSUEC(15,7);
    WAITV(14); if (TAGOK(0)) { CONSC(8,0);  } else pend |= 1u<<8;
    WAITV(12); if (TAGOK(1)) { CONSC(9,1);  } else pend |= 1u<<9;
    WAITV(10); if (TAGOK(2)) { CONSC(10,2); } else pend |= 1u<<10;
    WAITV(8);  if (TAGOK(3)) { CONSC(11,3); } else pend |= 1u<<11;
    WAITV(6);  if (TAGOK(4)) { CONSC(12,4); } else pend |= 1u<<12;
    WAITV(4);  if (TAGOK(5)) { CONSC(13,5); } else pend |= 1u<<13;
    WAITV(2);  if (TAGOK(6)) { CONSC(14,6); } else pend |= 1u<<14;
    WAITV(0);  if (TAGOK(7)) { CONSC(15,7); } else pend |= 1u<<15;

    // re-poll loop with livelock fuse: if the protocol ever wedges, fail
    // loudly (wrong data -> absmax fail) instead of hanging the queue.
    int fuse = 0;
    while (pend) {
      if (pend & 0x00FFu) {
        RISS(0); RISS(1); RISS(2); RISS(3); RISS(4); RISS(5); RISS(6); RISS(7);
        WAITV(0);
        RCON(0); RCON(1); RCON(2); RCON(3); RCON(4); RCON(5); RCON(6); RCON(7);
      }
      if (pend & 0xFF00u) {
        RISS(8); RISS(9); RISS(10); RISS(11); RISS(12); RISS(13); RISS(14); RISS(15);
        WAITV(0);
        RCON(8); RCON(9); RCON(10); RCON(11); RCON(12); RCON(13); RCON(14); RCON(15);
      }
      if (++fuse > 8192) break;
    }
    __builtin_amdgcn_sched_barrier(0);

    // ---- reissue emb gather for t+1 (overlaps gates/stores/next phase-1) ----
    {
      const float* eb = emb + (size_t)tok * 256;
#pragma unroll
      for (int e = 0; e < 8; ++e) {
        EA[2*e]   = *(const f32x4*)(eb + e * 32 + 8 * gq);
        EA[2*e+1] = *(const f32x4*)(eb + e * 32 + 8 * gq + 4);
      }
    }

    // ---- gates (cols: fin0=[i|f], fin1=[g|o]); no reduce needed ----
    f32x4 fin0 = accE[0] + accO[0];
    f32x4 fin1 = accE[1] + accO[1];
    fin0 += bias[0];
    fin1 += bias[1];
    const u32 tagn = (u32)(((t + 1) >> 1) & 1);
#pragma unroll
    for (int r = 0; r < 4; ++r) {
      float iv = fin0[r];
      float gv = fin1[r];
      float fv = __shfl_xor(iv, 8, 64);
      float ov = __shfl_xor(gv, 8, 64);
      float ii = sigm(iv);
      float ff = sigm(fv);
      float gg = tanhf_fast(gv);
      float oo = sigm(ov);
      float cn = ff * cst[r] + ii * gg;
      cst[r] = cn;
      float hnv = oo * tanhf_fast(cn);
      if (cl < 8) {
        int row = 4 * gq + r;
        int jj = 8 * w + cl;
        if (t < 511) {
          u16 hi = bf_hi(hnv);
          u16 lo = bf_hi(hnv - bf_up(hi));
          u32 word = ((u32)hi << 16) | ((u32)lo & 0xfffeu) | tagn;
          STORED(hn + row * 512 + jj, word);
        } else {
          int b = g * 16 + row;
          dout[320 + b * 512 + jj] = hnv;            // h_t
          dout[320 + 32768 + b * 512 + jj] = cn;     // c_t
        }
      }
    }
  }
}

// ---------------- final projection: out = h_T @ W_out^T + b_out --------------
__global__ void k_out(const float* __restrict__ Wout, const float* __restrict__ bout,
                      float* __restrict__ dout) {
  int i = threadIdx.x;
  if (i >= 320) return;
  int b = i / 5, o = i - b * 5;
  const float* hp = dout + 320 + b * 512;
  const float* wp = Wout + (size_t)o * 512;
  float s = 0.f;
#pragma unroll 4
  for (int k = 0; k < 512; k += 4) {
    s += hp[k] * wp[k] + hp[k + 1] * wp[k + 1] + hp[k + 2] * wp[k + 2] + hp[k + 3] * wp[k + 3];
  }
  dout[i] = s + bout[o];
}

extern "C" void kernel_launch(void* const* d_in, const int* in_sizes, int n_in,
                              void* d_out, int out_size, void* d_ws, size_t ws_size,
                              hipStream_t stream) {
  const int* x = (const int*)d_in[0];
  const float* emb = (const float*)d_in[1];
  const float* Wih = (const float*)d_in[2];
  const float* bih = (const float*)d_in[3];
  const float* Whh = (const float*)d_in[4];
  const float* bhh = (const float*)d_in[5];
  const float* Wout = (const float*)d_in[6];
  const float* bout = (const float*)d_in[7];
  float* out = (float*)d_out;
  uint8_t* ws = (uint8_t*)d_ws;

  hipLaunchKernelGGL(k_init, dim3(256), dim3(256), 0, stream, (u32*)ws);
  hipLaunchKernelGGL(k_prep, dim3(768), dim3(256), 0, stream, Wih, Whh, ws);
  hipLaunchKernelGGL(k_lstm, dim3(256), dim3(64), 0, stream, x, emb, bih, bhh, ws, out);
  hipLaunchKernelGGL(k_out, dim3(1), dim3(320), 0, stream, Wout, bout, out);
}

// Round 9
// 2071.315 us; speedup vs baseline: 1.2485x; 1.2485x over previous
//
#include <hip/hip_runtime.h>
#include <stdint.h>

typedef unsigned short u16;
typedef uint32_t u32;
typedef __attribute__((ext_vector_type(4))) u32 u32x4;
typedef __attribute__((ext_vector_type(8))) short v8s;
typedef __attribute__((ext_vector_type(4))) float f32x4;

// ---------------- workspace layout (bytes) ----------------
// h  : u32 [2 buf][4 grp][16 row][512 hid]   @ 0        (262144 B)
//      word = (bf16_hi<<16)|(bf16_lo&0xFFFE)|tag, tag=(t>>1)&1
// wf : u16 [64][2][24][64][16]               @ 262144   (6291456 B)
#define OFF_H  0
#define OFF_WF 262144

__device__ __forceinline__ u16 bf_hi(float v) {
  return (u16)(__builtin_bit_cast(u32, v) >> 16);
}
__device__ __forceinline__ float bf_up(u16 h) {
  return __builtin_bit_cast(float, (u32)h << 16);
}
__device__ __forceinline__ float tanhf_fast(float x) {
  float e = __expf(2.f * x);
  return 1.f - 2.f / (e + 1.f);
}
__device__ __forceinline__ float sigm(float x) {
  return 1.f / (1.f + __expf(-x));
}
// v_perm_b32 packers: pkhi(a,b) = (b&0xffff0000)|(a>>16); pklo = (b<<16)|(a&0xffff)
__device__ __forceinline__ u32 pkhi(u32 a, u32 b) { return __builtin_amdgcn_perm(b, a, 0x07060302u); }
__device__ __forceinline__ u32 pklo(u32 a, u32 b) { return __builtin_amdgcn_perm(b, a, 0x05040100u); }

// ---------------- init: buf0 = 0 (h0 valid, tag 0), buf1 = 1 (invalid at t=1)
__global__ void k_init(u32* h) {
  int i = blockIdx.x * 256 + threadIdx.x;   // 65536 words
  if (i < 65536) h[i] = (i < 32768) ? 0u : 1u;
}

// ---------------- pre-pack W_ih / W_hh into MFMA fragment order, bf16 hi/lo --
// chunk c: 0..7 -> W_ih (K'=c*32), 8..23 -> W_hh (K=(c-8)*32)
// B[k][n32] = W[R(n32)][k], R(n32) = (n32>>3)*512 + wg*8 + (n32&7)
__global__ void k_prep(const float* __restrict__ Wih, const float* __restrict__ Whh,
                       u16* __restrict__ wf) {
  int idx = blockIdx.x * 256 + threadIdx.x;
  if (idx >= 64 * 2 * 24 * 64) return;
  int lane = idx & 63;
  int r1 = idx >> 6;
  int c  = r1 % 24;
  int r2 = r1 / 24;
  int nt = r2 & 1;
  int wg = r2 >> 1;
  int n32 = nt * 16 + (lane & 15);
  int R = (n32 >> 3) * 512 + wg * 8 + (n32 & 7);
  int gq = lane >> 4;
  const float* src = (c < 8) ? (Wih + (size_t)R * 256 + c * 32 + 8 * gq)
                             : (Whh + (size_t)R * 512 + (c - 8) * 32 + 8 * gq);
  u16* d = wf + (size_t)idx * 16;
#pragma unroll
  for (int i = 0; i < 8; ++i) {
    float v = src[i];
    u16 hi = bf_hi(v);
    float lo = v - bf_up(hi);
    d[i] = hi;
    d[8 + i] = bf_hi(lo);
  }
}

// ---------------- asm helpers ----------------
#define LOADP(DST, PTR) \
  asm volatile("global_load_dwordx4 %0, %1, off" : "=v"(DST) : "v"(PTR))
#define LOADC(DST, PTR) \
  asm volatile("global_load_dwordx4 %0, %1, off sc0 sc1" : "=v"(DST) : "v"(PTR))
#define STORED(PTR, VAL) \
  asm volatile("global_store_dword %0, %1, off sc0 sc1" :: "v"(PTR), "v"(VAL) : "memory")

#define WAITV_(N) { asm volatile("s_waitcnt vmcnt(" #N ")" ::: "memory"); \
                    __builtin_amdgcn_sched_barrier(0); }
#define WAITV(N) WAITV_(N)

#define MFMA16(a, b, c) __builtin_amdgcn_mfma_f32_16x16x32_bf16((a), (b), (c), 0, 0, 0)
#define BC(x) __builtin_bit_cast(v8s, x)

// 6 MFMAs of one K-chunk: A (ah,al) x B {b0h,b0l,b1h,b1l} -> acc[0..1]
#define MM6(AH, AL, B) { \
  v8s b0h_ = BC((B)[0]), b0l_ = BC((B)[1]), b1h_ = BC((B)[2]), b1l_ = BC((B)[3]); \
  acc[0] = MFMA16((AH), b0h_, acc[0]); \
  acc[0] = MFMA16((AH), b0l_, acc[0]); \
  acc[0] = MFMA16((AL), b0h_, acc[0]); \
  acc[1] = MFMA16((AH), b1h_, acc[1]); \
  acc[1] = MFMA16((AH), b1l_, acc[1]); \
  acc[1] = MFMA16((AL), b1h_, acc[1]); }

// tag check of chunk j: all 8 LSBs == texp (wave-uniform verdict)
#define TAGOK(j) (__all((( (HA[2*(j)][0]^texp) | (HA[2*(j)][1]^texp) \
                         | (HA[2*(j)][2]^texp) | (HA[2*(j)][3]^texp) \
                         | (HA[2*(j)+1][0]^texp) | (HA[2*(j)+1][1]^texp) \
                         | (HA[2*(j)+1][2]^texp) | (HA[2*(j)+1][3]^texp)) & 1u) == 0u))

// consume chunk j: perm-unpack hi/lo + 6 MFMAs with BH[j]
#define CONSJ(j) { \
  u32x4 w0 = HA[2*(j)], w1 = HA[2*(j)+1]; \
  u32x4 hiw, low; \
  hiw[0] = pkhi(w0[0], w0[1]); hiw[1] = pkhi(w0[2], w0[3]); \
  hiw[2] = pkhi(w1[0], w1[1]); hiw[3] = pkhi(w1[2], w1[3]); \
  low[0] = pklo(w0[0], w0[1]); low[1] = pklo(w0[2], w0[3]); \
  low[2] = pklo(w1[0], w1[1]); low[3] = pklo(w1[2], w1[3]); \
  v8s ah = BC(hiw), al = BC(low); \
  MM6(ah, al, BH[j]); }

#define ISSUEJ(j) { LOADC(HA[2*(j)], pp[j]); LOADC(HA[2*(j)+1], pp[j] + 4); }
#define RISS(c)  if (pend & (1u<<(c))) ISSUEJ(c)
#define RCON(c)  if (pend & (1u<<(c))) { if (TAGOK(c)) { CONSJ(c); pend &= ~(1u<<(c)); } }

// ---------------- persistent recurrence kernel ----------------
// Grid 256 = 4 batch-groups x 64 WGs, 256 thr (4 waves). Group g owns rows
// [g*16,g*16+16); WG wg owns hidden octet [wg*8,wg*8+8) x4 gates. Waves split
// K 4-ways; one barrier/step (red double-buffered). All loop VMEM is inline
// asm with exact in-order vmcnt bookkeeping:
//   queue at loop top: [EA(4), ST(4)]; then +H(8) +tok(1).
//   phase-1 EA wait: vmcnt(13). chunk j wait: vmcnt(7-2j). tok: vmcnt(0).
// EA reissue happens AFTER __syncthreads so the barrier's implicit vmcnt(0)
// never drains an in-flight gather (round-6's hidden stall).
__global__ __launch_bounds__(256, 1) void k_lstm(
    const int* __restrict__ xin, const float* __restrict__ emb,
    const float* __restrict__ bih, const float* __restrict__ bhh,
    uint8_t* __restrict__ ws, float* __restrict__ dout)
{
  const int bid = blockIdx.x;
  const int wg = bid & 63;
  const int g  = bid >> 6;
  const int tid = threadIdx.x;
  const int wv = tid >> 6;
  const int lane = tid & 63;
  const int cl = lane & 15;
  const int gq = lane >> 4;

  u32* hbuf = (u32*)(ws + OFF_H);
  const u16* wf = (const u16*)(ws + OFF_WF);

  __shared__ f32x4 red[2][4][2][64];   // [t&1][src_wave][ntile][lane], 16 KiB

  float bias[2];
#pragma unroll
  for (int nt = 0; nt < 2; ++nt) {
    int n32 = nt * 16 + cl;
    int R = (n32 >> 3) * 512 + wg * 8 + (n32 & 7);
    bias[nt] = bih[R] + bhh[R];
  }

  // resident B-fragments (normal loads; compiler may AGPR them):
  // W_hh chunks (8 + wv + 4j), W_ih chunks (4J + wv); each {b0h,b0l,b1h,b1l}
  u32x4 BH[4][4], WB[2][4];
#pragma unroll
  for (int j = 0; j < 4; ++j) {
    const u32x4* p0 = (const u32x4*)(wf + ((((size_t)wg*2+0)*24 + (8 + wv + 4*j))*64 + lane)*16);
    const u32x4* p1 = (const u32x4*)(wf + ((((size_t)wg*2+1)*24 + (8 + wv + 4*j))*64 + lane)*16);
    BH[j][0] = p0[0]; BH[j][1] = p0[1];
    BH[j][2] = p1[0]; BH[j][3] = p1[1];
  }
#pragma unroll
  for (int J = 0; J < 2; ++J) {
    const u32x4* p0 = (const u32x4*)(wf + ((((size_t)wg*2+0)*24 + (4*J + wv))*64 + lane)*16);
    const u32x4* p1 = (const u32x4*)(wf + ((((size_t)wg*2+1)*24 + (4*J + wv))*64 + lane)*16);
    WB[J][0] = p0[0]; WB[J][1] = p0[1];
    WB[J][2] = p1[0]; WB[J][3] = p1[1];
  }

  const int brow = g * 16 + cl;                 // this lane's batch row
  const int koA = wv * 32 + 8 * gq;             // emb chunk wv
  const int koB = (4 + wv) * 32 + 8 * gq;       // emb chunk 4+wv

  // prologue: EA(t=0) via asm loads, fully drained
  u32x4 EA[4];
  {
    int tok0 = xin[brow * 512];
    const float* eb = emb + (size_t)tok0 * 256;
    LOADP(EA[0], eb + koA); LOADP(EA[1], eb + koA + 4);
    LOADP(EA[2], eb + koB); LOADP(EA[3], eb + koB + 4);
  }
  WAITV(0);

  float cst[4] = {0.f, 0.f, 0.f, 0.f};

  for (int t = 0; t < 512; ++t) {
    const u32* hc = hbuf + ((size_t)(t & 1) * 4 + g) * 8192;
    u32* hn = hbuf + ((size_t)((t + 1) & 1) * 4 + g) * 8192;
    const u32 texp = (u32)((t >> 1) & 1);
    const u32* pp[4];
    pp[0] = hc + cl * 512 + (wv + 0) * 32 + 8 * gq;
    pp[1] = hc + cl * 512 + (wv + 4) * 32 + 8 * gq;
    pp[2] = hc + cl * 512 + (wv + 8) * 32 + 8 * gq;
    pp[3] = hc + cl * 512 + (wv + 12) * 32 + 8 * gq;

    // ---- issue h loads + next-token load FIRST (overlap with phase-1) ----
    u32x4 HA[8];
    ISSUEJ(0); ISSUEJ(1); ISSUEJ(2); ISSUEJ(3);
    int tok;
    asm volatile("global_load_dword %0, %1, off"
                 : "=v"(tok) : "v"(xin + brow * 512 + ((t + 1) & 511)));
    __builtin_amdgcn_sched_barrier(0);

    // ---- phase-1: emb projection, x_hi * (w_hi + w_lo)  [EA after vmcnt(13)]
    WAITV(13);
    f32x4 acc[2] = {};
    {
      u32x4 h0, h1;
      h0[0] = pkhi(EA[0][0], EA[0][1]); h0[1] = pkhi(EA[0][2], EA[0][3]);
      h0[2] = pkhi(EA[1][0], EA[1][1]); h0[3] = pkhi(EA[1][2], EA[1][3]);
      h1[0] = pkhi(EA[2][0], EA[2][1]); h1[1] = pkhi(EA[2][2], EA[2][3]);
      h1[2] = pkhi(EA[3][0], EA[3][1]); h1[3] = pkhi(EA[3][2], EA[3][3]);
      v8s a0 = BC(h0), a1 = BC(h1);
      acc[0] = MFMA16(a0, BC(WB[0][0]), acc[0]);
      acc[0] = MFMA16(a0, BC(WB[0][1]), acc[0]);
      acc[1] = MFMA16(a0, BC(WB[0][2]), acc[1]);
      acc[1] = MFMA16(a0, BC(WB[0][3]), acc[1]);
      acc[0] = MFMA16(a1, BC(WB[1][0]), acc[0]);
      acc[0] = MFMA16(a1, BC(WB[1][1]), acc[0]);
      acc[1] = MFMA16(a1, BC(WB[1][2]), acc[1]);
      acc[1] = MFMA16(a1, BC(WB[1][3]), acc[1]);
    }

    // ---- counted tagged consume: chunk j ready at vmcnt(7-2j) ----
    u32 pend = 0;
    WAITV(7); if (TAGOK(0)) { CONSJ(0); } else pend |= 1u;
    WAITV(5); if (TAGOK(1)) { CONSJ(1); } else pend |= 2u;
    WAITV(3); if (TAGOK(2)) { CONSJ(2); } else pend |= 4u;
    WAITV(1); if (TAGOK(3)) { CONSJ(3); } else pend |= 8u;
    int fuse = 0;
    while (pend) {           // compact re-poll; fuse = loud failure, no hang
      RISS(0); RISS(1); RISS(2); RISS(3);
      WAITV(0);
      RCON(0); RCON(1); RCON(2); RCON(3);
      if (++fuse > 16384) break;
    }
    // tok is ready now; bind its reg through the wait so no use is hoisted
    asm volatile("s_waitcnt vmcnt(0)" : "+v"(tok) :: "memory");
    __builtin_amdgcn_sched_barrier(0);

    // ---- cross-wave K-reduction (double-buffered; barrier vmcnt(0) is free)
    red[t & 1][wv][0][lane] = acc[0];
    red[t & 1][wv][1][lane] = acc[1];
    __syncthreads();

    // ---- EA reissue for t+1 (AFTER barrier: no drain stall) ----
    {
      const float* eb = emb + (size_t)(u32)tok * 256;
      LOADP(EA[0], eb + koA); LOADP(EA[1], eb + koA + 4);
      LOADP(EA[2], eb + koB); LOADP(EA[3], eb + koB + 4);
    }

    f32x4 fin0 = red[t & 1][0][0][lane] + red[t & 1][1][0][lane]
               + red[t & 1][2][0][lane] + red[t & 1][3][0][lane];
    f32x4 fin1 = red[t & 1][0][1][lane] + red[t & 1][1][1][lane]
               + red[t & 1][2][1][lane] + red[t & 1][3][1][lane];
    fin0 += bias[0];
    fin1 += bias[1];

    // ---- gates: cols [i(0..7) f(8..15)] in fin0, [g(0..7) o(8..15)] in fin1
    const u32 tagn = (u32)(((t + 1) >> 1) & 1);
#pragma unroll
    for (int r = 0; r < 4; ++r) {
      float iv = fin0[r];
      float gv = fin1[r];
      float fv = __shfl_xor(iv, 8, 64);
      float ov = __shfl_xor(gv, 8, 64);
      float ii = sigm(iv);
      float ff = sigm(fv);
      float gg = tanhf_fast(gv);
      float oo = sigm(ov);
      float cn = ff * cst[r] + ii * gg;
      cst[r] = cn;
      float hnv = oo * tanhf_fast(cn);
      // wave wv stores rows 4*wv+r (gq==wv lanes): 4-way parallel store issue
      if (gq == wv && cl < 8) {
        int row = 4 * gq + r;
        int jj = wg * 8 + cl;
        if (t < 511) {
          u16 hi = bf_hi(hnv);
          u16 lo = bf_hi(hnv - bf_up(hi));
          u32 word = ((u32)hi << 16) | ((u32)lo & 0xfffeu) | tagn;
          STORED(hn + row * 512 + jj, word);
        } else {
          int b = g * 16 + row;
          dout[320 + b * 512 + jj] = hnv;            // h_t
          dout[320 + 32768 + b * 512 + jj] = cn;     // c_t
        }
      }
    }
  }
}

// ---------------- final projection: out = h_T @ W_out^T + b_out --------------
__global__ void k_out(const float* __restrict__ Wout, const float* __restrict__ bout,
                      float* __restrict__ dout) {
  int i = threadIdx.x;
  if (i >= 320) return;
  int b = i / 5, o = i - b * 5;
  const float* hp = dout + 320 + b * 512;
  const float* wp = Wout + (size_t)o * 512;
  float s = 0.f;
#pragma unroll 4
  for (int k = 0; k < 512; k += 4) {
    s += hp[k] * wp[k] + hp[k + 1] * wp[k + 1] + hp[k + 2] * wp[k + 2] + hp[k + 3] * wp[k + 3];
  }
  dout[i] = s + bout[o];
}

extern "C" void kernel_launch(void* const* d_in, const int* in_sizes, int n_in,
                              void* d_out, int out_size, void* d_ws, size_t ws_size,
                              hipStream_t stream) {
  const int* x = (const int*)d_in[0];
  const float* emb = (const float*)d_in[1];
  const float* Wih = (const float*)d_in[2];
  const float* bih = (const float*)d_in[3];
  const float* Whh = (const float*)d_in[4];
  const float* bhh = (const float*)d_in[5];
  const float* Wout = (const float*)d_in[6];
  const float* bout = (const float*)d_in[7];
  float* out = (float*)d_out;
  uint8_t* ws = (uint8_t*)d_ws;

  hipLaunchKernelGGL(k_init, dim3(256), dim3(256), 0, stream, (u32*)ws);
  hipLaunchKernelGGL(k_prep, dim3(768), dim3(256), 0, stream, Wih, Whh, (u16*)(ws + OFF_WF));
  hipLaunchKernelGGL(k_lstm, dim3(256), dim3(256), 0, stream, x, emb, bih, bhh, ws, out);
  hipLaunchKernelGGL(k_out, dim3(1), dim3(320), 0, stream, Wout, bout, out);
}

// Round 10
// 1991.628 us; speedup vs baseline: 1.2985x; 1.0400x over previous
//
#include <hip/hip_runtime.h>
#include <stdint.h>

typedef unsigned short u16;
typedef uint32_t u32;
typedef __attribute__((ext_vector_type(4))) u32 u32x4;
typedef __attribute__((ext_vector_type(8))) short v8s;
typedef __attribute__((ext_vector_type(4))) float f32x4;

// ---------------- workspace layout (bytes) ----------------
// h  : u32 [2 buf][4 grp][16 row][512 hid]   @ 0        (262144 B)
//      word = (bf16_hi<<16)|(bf16_lo&0xFFFE)|tag, tag=(t>>1)&1
// wf : u16 [64][2][24][64][16]               @ 262144   (6291456 B)
#define OFF_H  0
#define OFF_WF 262144

__device__ __forceinline__ u16 bf_hi(float v) {
  return (u16)(__builtin_bit_cast(u32, v) >> 16);
}
__device__ __forceinline__ float bf_up(u16 h) {
  return __builtin_bit_cast(float, (u32)h << 16);
}
__device__ __forceinline__ float tanhf_fast(float x) {
  float e = __expf(2.f * x);
  return 1.f - 2.f / (e + 1.f);
}
__device__ __forceinline__ float sigm(float x) {
  return 1.f / (1.f + __expf(-x));
}
// v_perm_b32 packers: pkhi(a,b) = (b&0xffff0000)|(a>>16); pklo = (b<<16)|(a&0xffff)
__device__ __forceinline__ u32 pkhi(u32 a, u32 b) { return __builtin_amdgcn_perm(b, a, 0x07060302u); }
__device__ __forceinline__ u32 pklo(u32 a, u32 b) { return __builtin_amdgcn_perm(b, a, 0x05040100u); }

// ---------------- init: buf0 = 0 (h0 valid, tag 0), buf1 = 1 (invalid at t=1)
__global__ void k_init(u32* h) {
  int i = blockIdx.x * 256 + threadIdx.x;   // 65536 words
  if (i < 65536) h[i] = (i < 32768) ? 0u : 1u;
}

// ---------------- pre-pack W_ih / W_hh into MFMA fragment order, bf16 hi/lo --
// chunk c: 0..7 -> W_ih (K'=c*32), 8..23 -> W_hh (K=(c-8)*32)
// B[k][n32] = W[R(n32)][k], R(n32) = (n32>>3)*512 + wg*8 + (n32&7)
__global__ void k_prep(const float* __restrict__ Wih, const float* __restrict__ Whh,
                       u16* __restrict__ wf) {
  int idx = blockIdx.x * 256 + threadIdx.x;
  if (idx >= 64 * 2 * 24 * 64) return;
  int lane = idx & 63;
  int r1 = idx >> 6;
  int c  = r1 % 24;
  int r2 = r1 / 24;
  int nt = r2 & 1;
  int wg = r2 >> 1;
  int n32 = nt * 16 + (lane & 15);
  int R = (n32 >> 3) * 512 + wg * 8 + (n32 & 7);
  int gq = lane >> 4;
  const float* src = (c < 8) ? (Wih + (size_t)R * 256 + c * 32 + 8 * gq)
                             : (Whh + (size_t)R * 512 + (c - 8) * 32 + 8 * gq);
  u16* d = wf + (size_t)idx * 16;
#pragma unroll
  for (int i = 0; i < 8; ++i) {
    float v = src[i];
    u16 hi = bf_hi(v);
    float lo = v - bf_up(hi);
    d[i] = hi;
    d[8 + i] = bf_hi(lo);
  }
}

// ---------------- asm helpers ----------------
#define LOADP(DST, PTR) \
  asm volatile("global_load_dwordx4 %0, %1, off" : "=v"(DST) : "v"(PTR))
#define LOADC(DST, PTR) \
  asm volatile("global_load_dwordx4 %0, %1, off sc0 sc1" : "=v"(DST) : "v"(PTR))
#define STORED(PTR, VAL) \
  asm volatile("global_store_dword %0, %1, off sc0 sc1" :: "v"(PTR), "v"(VAL) : "memory")

#define WAITV_(N) { asm volatile("s_waitcnt vmcnt(" #N ")" ::: "memory"); \
                    __builtin_amdgcn_sched_barrier(0); }
#define WAITV(N) WAITV_(N)

#define MFMA16(a, b, c) __builtin_amdgcn_mfma_f32_16x16x32_bf16((a), (b), (c), 0, 0, 0)
#define BC(x) __builtin_bit_cast(v8s, x)

// 6 MFMAs of one K-chunk: A (ah,al) x B {b0h,b0l,b1h,b1l} -> acc[0..1]
#define MM6(AH, AL, B) { \
  v8s b0h_ = BC((B)[0]), b0l_ = BC((B)[1]), b1h_ = BC((B)[2]), b1l_ = BC((B)[3]); \
  acc[0] = MFMA16((AH), b0h_, acc[0]); \
  acc[0] = MFMA16((AH), b0l_, acc[0]); \
  acc[0] = MFMA16((AL), b0h_, acc[0]); \
  acc[1] = MFMA16((AH), b1h_, acc[1]); \
  acc[1] = MFMA16((AH), b1l_, acc[1]); \
  acc[1] = MFMA16((AL), b1h_, acc[1]); }

// tag check of chunk j: all 8 LSBs == texp (wave-uniform verdict)
#define TAGOK(j) (__all((( (HA[2*(j)][0]^texp) | (HA[2*(j)][1]^texp) \
                         | (HA[2*(j)][2]^texp) | (HA[2*(j)][3]^texp) \
                         | (HA[2*(j)+1][0]^texp) | (HA[2*(j)+1][1]^texp) \
                         | (HA[2*(j)+1][2]^texp) | (HA[2*(j)+1][3]^texp)) & 1u) == 0u))

// consume chunk j: perm-unpack hi/lo + 6 MFMAs with BH[j]
#define CONSJ(j) { \
  u32x4 w0 = HA[2*(j)], w1 = HA[2*(j)+1]; \
  u32x4 hiw, low; \
  hiw[0] = pkhi(w0[0], w0[1]); hiw[1] = pkhi(w0[2], w0[3]); \
  hiw[2] = pkhi(w1[0], w1[1]); hiw[3] = pkhi(w1[2], w1[3]); \
  low[0] = pklo(w0[0], w0[1]); low[1] = pklo(w0[2], w0[3]); \
  low[2] = pklo(w1[0], w1[1]); low[3] = pklo(w1[2], w1[3]); \
  v8s ah = BC(hiw), al = BC(low); \
  MM6(ah, al, BH[j]); }

#define ISSUEJ(j) { LOADC(HA[2*(j)], pp[j]); LOADC(HA[2*(j)+1], pp[j] + 4); }
#define RISS(c)  if (pend & (1u<<(c))) ISSUEJ(c)
#define RCON(c)  if (pend & (1u<<(c))) { if (TAGOK(c)) { CONSJ(c); pend &= ~(1u<<(c)); } }

// ---------------- persistent recurrence kernel ----------------
// Grid 256 = 4 batch-groups x 64 WGs, 256 thr (4 waves). Group g owns rows
// [g*16,g*16+16); WG wg owns hidden octet [wg*8,wg*8+8) x4 gates. Waves split
// K 4-ways; one barrier/step (red double-buffered). All loop VMEM is inline
// asm with exact in-order vmcnt bookkeeping:
//   loop-top queue: [EA(4), ST(4)].  phase-1 EA wait: vmcnt(4).
//   THEN issue H(8)+tok (late sampling: producers get the phase-1 window —
//   round-9 lesson: early sampling multiplies re-poll rounds).
//   chunk j ready at vmcnt(7-2j); tok at vmcnt(0).
// EA reissue AFTER __syncthreads so the barrier's implicit vmcnt(0) drain
// never waits on an in-flight gather.
__global__ __launch_bounds__(256, 1) void k_lstm(
    const int* __restrict__ xin, const float* __restrict__ emb,
    const float* __restrict__ bih, const float* __restrict__ bhh,
    uint8_t* __restrict__ ws, float* __restrict__ dout)
{
  const int bid = blockIdx.x;
  const int wg = bid & 63;
  const int g  = bid >> 6;
  const int tid = threadIdx.x;
  const int wv = tid >> 6;
  const int lane = tid & 63;
  const int cl = lane & 15;
  const int gq = lane >> 4;

  u32* hbuf = (u32*)(ws + OFF_H);
  const u16* wf = (const u16*)(ws + OFF_WF);

  __shared__ f32x4 red[2][4][2][64];   // [t&1][src_wave][ntile][lane], 16 KiB

  float bias[2];
#pragma unroll
  for (int nt = 0; nt < 2; ++nt) {
    int n32 = nt * 16 + cl;
    int R = (n32 >> 3) * 512 + wg * 8 + (n32 & 7);
    bias[nt] = bih[R] + bhh[R];
  }

  // resident B-fragments (normal loads; compiler may AGPR them):
  // W_hh chunks (8 + wv + 4j), W_ih chunks (4J + wv); each {b0h,b0l,b1h,b1l}
  u32x4 BH[4][4], WB[2][4];
#pragma unroll
  for (int j = 0; j < 4; ++j) {
    const u32x4* p0 = (const u32x4*)(wf + ((((size_t)wg*2+0)*24 + (8 + wv + 4*j))*64 + lane)*16);
    const u32x4* p1 = (const u32x4*)(wf + ((((size_t)wg*2+1)*24 + (8 + wv + 4*j))*64 + lane)*16);
    BH[j][0] = p0[0]; BH[j][1] = p0[1];
    BH[j][2] = p1[0]; BH[j][3] = p1[1];
  }
#pragma unroll
  for (int J = 0; J < 2; ++J) {
    const u32x4* p0 = (const u32x4*)(wf + ((((size_t)wg*2+0)*24 + (4*J + wv))*64 + lane)*16);
    const u32x4* p1 = (const u32x4*)(wf + ((((size_t)wg*2+1)*24 + (4*J + wv))*64 + lane)*16);
    WB[J][0] = p0[0]; WB[J][1] = p0[1];
    WB[J][2] = p1[0]; WB[J][3] = p1[1];
  }

  const int brow = g * 16 + cl;                 // this lane's batch row
  const int koA = wv * 32 + 8 * gq;             // emb chunk wv
  const int koB = (4 + wv) * 32 + 8 * gq;       // emb chunk 4+wv

  // prologue: EA(t=0) via asm loads, fully drained
  u32x4 EA[4];
  {
    int tok0 = xin[brow * 512];
    const float* eb = emb + (size_t)tok0 * 256;
    LOADP(EA[0], eb + koA); LOADP(EA[1], eb + koA + 4);
    LOADP(EA[2], eb + koB); LOADP(EA[3], eb + koB + 4);
  }
  WAITV(0);

  float cst[4] = {0.f, 0.f, 0.f, 0.f};

  for (int t = 0; t < 512; ++t) {
    const u32* hc = hbuf + ((size_t)(t & 1) * 4 + g) * 8192;
    u32* hn = hbuf + ((size_t)((t + 1) & 1) * 4 + g) * 8192;
    const u32 texp = (u32)((t >> 1) & 1);
    const u32* pp[4];
    pp[0] = hc + cl * 512 + (wv + 0) * 32 + 8 * gq;
    pp[1] = hc + cl * 512 + (wv + 4) * 32 + 8 * gq;
    pp[2] = hc + cl * 512 + (wv + 8) * 32 + 8 * gq;
    pp[3] = hc + cl * 512 + (wv + 12) * 32 + 8 * gq;

    // ---- phase-1: emb projection, x_hi * (w_hi + w_lo)   [wait EA only] ----
    WAITV(4);
    f32x4 acc[2] = {};
    {
      u32x4 h0, h1;
      h0[0] = pkhi(EA[0][0], EA[0][1]); h0[1] = pkhi(EA[0][2], EA[0][3]);
      h0[2] = pkhi(EA[1][0], EA[1][1]); h0[3] = pkhi(EA[1][2], EA[1][3]);
      h1[0] = pkhi(EA[2][0], EA[2][1]); h1[1] = pkhi(EA[2][2], EA[2][3]);
      h1[2] = pkhi(EA[3][0], EA[3][1]); h1[3] = pkhi(EA[3][2], EA[3][3]);
      v8s a0 = BC(h0), a1 = BC(h1);
      acc[0] = MFMA16(a0, BC(WB[0][0]), acc[0]);
      acc[0] = MFMA16(a0, BC(WB[0][1]), acc[0]);
      acc[1] = MFMA16(a0, BC(WB[0][2]), acc[1]);
      acc[1] = MFMA16(a0, BC(WB[0][3]), acc[1]);
      acc[0] = MFMA16(a1, BC(WB[1][0]), acc[0]);
      acc[0] = MFMA16(a1, BC(WB[1][1]), acc[0]);
      acc[1] = MFMA16(a1, BC(WB[1][2]), acc[1]);
      acc[1] = MFMA16(a1, BC(WB[1][3]), acc[1]);
    }

    // ---- NOW sample h (late): issue 8 h loads + next-token load ----
    u32x4 HA[8];
    ISSUEJ(0); ISSUEJ(1); ISSUEJ(2); ISSUEJ(3);
    int tok;
    asm volatile("global_load_dword %0, %1, off"
                 : "=v"(tok) : "v"(xin + brow * 512 + ((t + 1) & 511)));
    __builtin_amdgcn_sched_barrier(0);

    // ---- counted tagged consume: queue [ST4,H8,tok]; chunk j at vmcnt(7-2j)
    u32 pend = 0;
    WAITV(7); if (TAGOK(0)) { CONSJ(0); } else pend |= 1u;
    WAITV(5); if (TAGOK(1)) { CONSJ(1); } else pend |= 2u;
    WAITV(3); if (TAGOK(2)) { CONSJ(2); } else pend |= 4u;
    WAITV(1); if (TAGOK(3)) { CONSJ(3); } else pend |= 8u;
    int fuse = 0;
    while (pend) {           // backoff re-poll; fuse = loud failure, no hang
      __builtin_amdgcn_s_sleep(1);
      RISS(0); RISS(1); RISS(2); RISS(3);
      WAITV(0);
      RCON(0); RCON(1); RCON(2); RCON(3);
      if (++fuse > 16384) break;
    }
    // tok is ready now; bind its reg through the wait so no use is hoisted
    asm volatile("s_waitcnt vmcnt(0)" : "+v"(tok) :: "memory");
    __builtin_amdgcn_sched_barrier(0);

    // ---- cross-wave K-reduction (double-buffered; barrier vmcnt(0) is free)
    red[t & 1][wv][0][lane] = acc[0];
    red[t & 1][wv][1][lane] = acc[1];
    __syncthreads();

    // ---- EA reissue for t+1 (AFTER barrier: no drain stall) ----
    {
      const float* eb = emb + (size_t)(u32)tok * 256;
      LOADP(EA[0], eb + koA); LOADP(EA[1], eb + koA + 4);
      LOADP(EA[2], eb + koB); LOADP(EA[3], eb + koB + 4);
    }

    f32x4 fin0 = red[t & 1][0][0][lane] + red[t & 1][1][0][lane]
               + red[t & 1][2][0][lane] + red[t & 1][3][0][lane];
    f32x4 fin1 = red[t & 1][0][1][lane] + red[t & 1][1][1][lane]
               + red[t & 1][2][1][lane] + red[t & 1][3][1][lane];
    fin0 += bias[0];
    fin1 += bias[1];

    // ---- gates: cols [i(0..7) f(8..15)] in fin0, [g(0..7) o(8..15)] in fin1
    const u32 tagn = (u32)(((t + 1) >> 1) & 1);
#pragma unroll
    for (int r = 0; r < 4; ++r) {
      float iv = fin0[r];
      float gv = fin1[r];
      float fv = __shfl_xor(iv, 8, 64);
      float ov = __shfl_xor(gv, 8, 64);
      float ii = sigm(iv);
      float ff = sigm(fv);
      float gg = tanhf_fast(gv);
      float oo = sigm(ov);
      float cn = ff * cst[r] + ii * gg;
      cst[r] = cn;
      float hnv = oo * tanhf_fast(cn);
      // wave wv stores rows 4*wv+r (gq==wv lanes): 4-way parallel store issue
      if (gq == wv && cl < 8) {
        int row = 4 * gq + r;
        int jj = wg * 8 + cl;
        if (t < 511) {
          u16 hi = bf_hi(hnv);
          u16 lo = bf_hi(hnv - bf_up(hi));
          u32 word = ((u32)hi << 16) | ((u32)lo & 0xfffeu) | tagn;
          STORED(hn + row * 512 + jj, word);
        } else {
          int b = g * 16 + row;
          dout[320 + b * 512 + jj] = hnv;            // h_t
          dout[320 + 32768 + b * 512 + jj] = cn;     // c_t
        }
      }
    }
  }
}

// ---------------- final projection: out = h_T @ W_out^T + b_out --------------
__global__ void k_out(const float* __restrict__ Wout, const float* __restrict__ bout,
                      float* __restrict__ dout) {
  int i = threadIdx.x;
  if (i >= 320) return;
  int b = i / 5, o = i - b * 5;
  const float* hp = dout + 320 + b * 512;
  const float* wp = Wout + (size_t)o * 512;
  float s = 0.f;
#pragma unroll 4
  for (int k = 0; k < 512; k += 4) {
    s += hp[k] * wp[k] + hp[k + 1] * wp[k + 1] + hp[k + 2] * wp[k + 2] + hp[k + 3] * wp[k + 3];
  }
  dout[i] = s + bout[o];
}

extern "C" void kernel_launch(void* const* d_in, const int* in_sizes, int n_in,
                              void* d_out, int out_size, void* d_ws, size_t ws_size,
                              hipStream_t stream) {
  const int* x = (const int*)d_in[0];
  const float* emb = (const float*)d_in[1];
  const float* Wih = (const float*)d_in[2];
  const float* bih = (const float*)d_in[3];
  const float* Whh = (const float*)d_in[4];
  const float* bhh = (const float*)d_in[5];
  const float* Wout = (const float*)d_in[6];
  const float* bout = (const float*)d_in[7];
  float* out = (float*)d_out;
  uint8_t* ws = (uint8_t*)d_ws;

  hipLaunchKernelGGL(k_init, dim3(256), dim3(256), 0, stream, (u32*)ws);
  hipLaunchKernelGGL(k_prep, dim3(768), dim3(256), 0, stream, Wih, Whh, (u16*)(ws + OFF_WF));
  hipLaunchKernelGGL(k_lstm, dim3(256), dim3(256), 0, stream, x, emb, bih, bhh, ws, out);
  hipLaunchKernelGGL(k_out, dim3(1), dim3(320), 0, stream, Wout, bout, out);
}

// Round 11
// 1675.823 us; speedup vs baseline: 1.5432x; 1.1884x over previous
//
#include <hip/hip_runtime.h>
#include <stdint.h>

typedef unsigned short u16;
typedef uint32_t u32;
typedef __attribute__((ext_vector_type(4))) u32 u32x4;
typedef __attribute__((ext_vector_type(8))) short v8s;
typedef __attribute__((ext_vector_type(4))) float f32x4;

// ---------------- workspace layout (bytes) ----------------
// h  : u32 [2 buf][4 grp][16 row][512 hid]   @ 0        (262144 B)
//      word = (bf16_hi<<16)|(bf16_lo&0xFFFE)|tag, tag=(t>>1)&1
// wf : u16 [64][2][24][64][16]               @ 262144   (6291456 B)
#define OFF_H  0
#define OFF_WF 262144

__device__ __forceinline__ u16 bf_hi(float v) {
  return (u16)(__builtin_bit_cast(u32, v) >> 16);
}
__device__ __forceinline__ float bf_up(u16 h) {
  return __builtin_bit_cast(float, (u32)h << 16);
}
__device__ __forceinline__ float tanhf_fast(float x) {
  float e = __expf(2.f * x);
  return 1.f - 2.f / (e + 1.f);
}
__device__ __forceinline__ float sigm(float x) {
  return 1.f / (1.f + __expf(-x));
}
// v_perm_b32 packers: pkhi(a,b) = (b&0xffff0000)|(a>>16); pklo = (b<<16)|(a&0xffff)
__device__ __forceinline__ u32 pkhi(u32 a, u32 b) { return __builtin_amdgcn_perm(b, a, 0x07060302u); }
__device__ __forceinline__ u32 pklo(u32 a, u32 b) { return __builtin_amdgcn_perm(b, a, 0x05040100u); }

// ---------------- init: buf0 = 0 (h0 valid, tag 0), buf1 = 1 (invalid at t=1)
__global__ void k_init(u32* h) {
  int i = blockIdx.x * 256 + threadIdx.x;   // 65536 words
  if (i < 65536) h[i] = (i < 32768) ? 0u : 1u;
}

// ---------------- pre-pack W_ih / W_hh into MFMA fragment order, bf16 hi/lo --
// chunk c: 0..7 -> W_ih (K'=c*32), 8..23 -> W_hh (K=(c-8)*32)
// B[k][n32] = W[R(n32)][k], R(n32) = (n32>>3)*512 + wg*8 + (n32&7)
__global__ void k_prep(const float* __restrict__ Wih, const float* __restrict__ Whh,
                       u16* __restrict__ wf) {
  int idx = blockIdx.x * 256 + threadIdx.x;
  if (idx >= 64 * 2 * 24 * 64) return;
  int lane = idx & 63;
  int r1 = idx >> 6;
  int c  = r1 % 24;
  int r2 = r1 / 24;
  int nt = r2 & 1;
  int wg = r2 >> 1;
  int n32 = nt * 16 + (lane & 15);
  int R = (n32 >> 3) * 512 + wg * 8 + (n32 & 7);
  int gq = lane >> 4;
  const float* src = (c < 8) ? (Wih + (size_t)R * 256 + c * 32 + 8 * gq)
                             : (Whh + (size_t)R * 512 + (c - 8) * 32 + 8 * gq);
  u16* d = wf + (size_t)idx * 16;
#pragma unroll
  for (int i = 0; i < 8; ++i) {
    float v = src[i];
    u16 hi = bf_hi(v);
    float lo = v - bf_up(hi);
    d[i] = hi;
    d[8 + i] = bf_hi(lo);
  }
}

// ---------------- asm helpers ----------------
#define LOADP(DST, PTR) \
  asm volatile("global_load_dwordx4 %0, %1, off" : "=v"(DST) : "v"(PTR))
#define LOADC(DST, PTR) \
  asm volatile("global_load_dwordx4 %0, %1, off sc0 sc1" : "=v"(DST) : "v"(PTR))
#define STORED(PTR, VAL) \
  asm volatile("global_store_dword %0, %1, off sc0 sc1" :: "v"(PTR), "v"(VAL) : "memory")

#define WAITV_(N) { asm volatile("s_waitcnt vmcnt(" #N ")" ::: "memory"); \
                    __builtin_amdgcn_sched_barrier(0); }
#define WAITV(N) WAITV_(N)

#define MFMA16(a, b, c) __builtin_amdgcn_mfma_f32_16x16x32_bf16((a), (b), (c), 0, 0, 0)
#define BC(x) __builtin_bit_cast(v8s, x)

// 6 MFMAs of one K-chunk: A (ah,al) x B {b0h,b0l,b1h,b1l} -> acc[0..1]
#define MM6(AH, AL, B) { \
  v8s b0h_ = BC((B)[0]), b0l_ = BC((B)[1]), b1h_ = BC((B)[2]), b1l_ = BC((B)[3]); \
  acc[0] = MFMA16((AH), b0h_, acc[0]); \
  acc[0] = MFMA16((AH), b0l_, acc[0]); \
  acc[0] = MFMA16((AL), b0h_, acc[0]); \
  acc[1] = MFMA16((AH), b1h_, acc[1]); \
  acc[1] = MFMA16((AH), b1l_, acc[1]); \
  acc[1] = MFMA16((AL), b1h_, acc[1]); }

// tag check of chunk j: all 8 LSBs == texp (wave-uniform verdict)
#define TAGOK(j) (__all((( (HA[2*(j)][0]^texp) | (HA[2*(j)][1]^texp) \
                         | (HA[2*(j)][2]^texp) | (HA[2*(j)][3]^texp) \
                         | (HA[2*(j)+1][0]^texp) | (HA[2*(j)+1][1]^texp) \
                         | (HA[2*(j)+1][2]^texp) | (HA[2*(j)+1][3]^texp)) & 1u) == 0u))

// consume chunk j: perm-unpack hi/lo + 6 MFMAs with BH[j]
#define CONSJ(j) { \
  u32x4 w0 = HA[2*(j)], w1 = HA[2*(j)+1]; \
  u32x4 hiw, low; \
  hiw[0] = pkhi(w0[0], w0[1]); hiw[1] = pkhi(w0[2], w0[3]); \
  hiw[2] = pkhi(w1[0], w1[1]); hiw[3] = pkhi(w1[2], w1[3]); \
  low[0] = pklo(w0[0], w0[1]); low[1] = pklo(w0[2], w0[3]); \
  low[2] = pklo(w1[0], w1[1]); low[3] = pklo(w1[2], w1[3]); \
  v8s ah = BC(hiw), al = BC(low); \
  MM6(ah, al, BH[j]); }

#define ISSUEJ(j) { LOADC(HA[2*(j)], pp[j]); LOADC(HA[2*(j)+1], pp[j] + 4); }
#define RISS(c)  if (pend & (1u<<(c))) ISSUEJ(c)
#define RCON(c)  if (pend & (1u<<(c))) { if (TAGOK(c)) { CONSJ(c); pend &= ~(1u<<(c)); } }

// ---------------- persistent recurrence kernel ----------------
// Grid 256 = 4 batch-groups x 64 WGs, 256 thr (4 waves). Group g owns rows
// [g*16,g*16+16); WG wg owns hidden octet [wg*8,wg*8+8) x4 gates. Waves split
// K 4-ways; one barrier/step (red double-buffered).
//
// SELF-TIMED RING + ADAPTIVE SAMPLING DELAY (round-10 lesson): sampling h too
// early costs a full re-poll round (~0.5-0.7us reissue RT + tag checks);
// sampling late costs 26ns/unit. Each wave tunes `delay` (s_sleep(1) units):
// first-pass miss -> +8 (cap 64); clean hit -> -1 (floor 0). Equilibrium miss
// rate ~1/9 -> re-poll rounds nearly vanish; negative feedback is stable.
//
// vmcnt bookkeeping: loop-top queue [EA4, ST4]; phase-1 waits vmcnt(4) (EA
// only). Then adaptive sleep, then issue H8+tok: chunk j ready at vmcnt(7-2j),
// tok at vmcnt(0). EA reissue AFTER __syncthreads (barrier drain is free).
__global__ __launch_bounds__(256, 1) void k_lstm(
    const int* __restrict__ xin, const float* __restrict__ emb,
    const float* __restrict__ bih, const float* __restrict__ bhh,
    uint8_t* __restrict__ ws, float* __restrict__ dout)
{
  const int bid = blockIdx.x;
  const int wg = bid & 63;
  const int g  = bid >> 6;
  const int tid = threadIdx.x;
  const int wv = tid >> 6;
  const int lane = tid & 63;
  const int cl = lane & 15;
  const int gq = lane >> 4;

  u32* hbuf = (u32*)(ws + OFF_H);
  const u16* wf = (const u16*)(ws + OFF_WF);

  __shared__ f32x4 red[2][4][2][64];   // [t&1][src_wave][ntile][lane], 16 KiB

  float bias[2];
#pragma unroll
  for (int nt = 0; nt < 2; ++nt) {
    int n32 = nt * 16 + cl;
    int R = (n32 >> 3) * 512 + wg * 8 + (n32 & 7);
    bias[nt] = bih[R] + bhh[R];
  }

  // resident B-fragments (normal loads; compiler may AGPR them):
  // W_hh chunks (8 + wv + 4j), W_ih chunks (4J + wv); each {b0h,b0l,b1h,b1l}
  u32x4 BH[4][4], WB[2][4];
#pragma unroll
  for (int j = 0; j < 4; ++j) {
    const u32x4* p0 = (const u32x4*)(wf + ((((size_t)wg*2+0)*24 + (8 + wv + 4*j))*64 + lane)*16);
    const u32x4* p1 = (const u32x4*)(wf + ((((size_t)wg*2+1)*24 + (8 + wv + 4*j))*64 + lane)*16);
    BH[j][0] = p0[0]; BH[j][1] = p0[1];
    BH[j][2] = p1[0]; BH[j][3] = p1[1];
  }
#pragma unroll
  for (int J = 0; J < 2; ++J) {
    const u32x4* p0 = (const u32x4*)(wf + ((((size_t)wg*2+0)*24 + (4*J + wv))*64 + lane)*16);
    const u32x4* p1 = (const u32x4*)(wf + ((((size_t)wg*2+1)*24 + (4*J + wv))*64 + lane)*16);
    WB[J][0] = p0[0]; WB[J][1] = p0[1];
    WB[J][2] = p1[0]; WB[J][3] = p1[1];
  }

  const int brow = g * 16 + cl;                 // this lane's batch row
  const int koA = wv * 32 + 8 * gq;             // emb chunk wv
  const int koB = (4 + wv) * 32 + 8 * gq;       // emb chunk 4+wv

  // prologue: EA(t=0) via asm loads, fully drained
  u32x4 EA[4];
  {
    int tok0 = xin[brow * 512];
    const float* eb = emb + (size_t)tok0 * 256;
    LOADP(EA[0], eb + koA); LOADP(EA[1], eb + koA + 4);
    LOADP(EA[2], eb + koB); LOADP(EA[3], eb + koB + 4);
  }
  WAITV(0);

  float cst[4] = {0.f, 0.f, 0.f, 0.f};
  int delay = 16;                // adaptive sampling delay, s_sleep(1) units

  for (int t = 0; t < 512; ++t) {
    const u32* hc = hbuf + ((size_t)(t & 1) * 4 + g) * 8192;
    u32* hn = hbuf + ((size_t)((t + 1) & 1) * 4 + g) * 8192;
    const u32 texp = (u32)((t >> 1) & 1);
    const u32* pp[4];
    pp[0] = hc + cl * 512 + (wv + 0) * 32 + 8 * gq;
    pp[1] = hc + cl * 512 + (wv + 4) * 32 + 8 * gq;
    pp[2] = hc + cl * 512 + (wv + 8) * 32 + 8 * gq;
    pp[3] = hc + cl * 512 + (wv + 12) * 32 + 8 * gq;

    // ---- phase-1: emb projection, x_hi * (w_hi + w_lo)   [wait EA only] ----
    WAITV(4);
    f32x4 acc[2] = {};
    {
      u32x4 h0, h1;
      h0[0] = pkhi(EA[0][0], EA[0][1]); h0[1] = pkhi(EA[0][2], EA[0][3]);
      h0[2] = pkhi(EA[1][0], EA[1][1]); h0[3] = pkhi(EA[1][2], EA[1][3]);
      h1[0] = pkhi(EA[2][0], EA[2][1]); h1[1] = pkhi(EA[2][2], EA[2][3]);
      h1[2] = pkhi(EA[3][0], EA[3][1]); h1[3] = pkhi(EA[3][2], EA[3][3]);
      v8s a0 = BC(h0), a1 = BC(h1);
      acc[0] = MFMA16(a0, BC(WB[0][0]), acc[0]);
      acc[0] = MFMA16(a0, BC(WB[0][1]), acc[0]);
      acc[1] = MFMA16(a0, BC(WB[0][2]), acc[1]);
      acc[1] = MFMA16(a0, BC(WB[0][3]), acc[1]);
      acc[0] = MFMA16(a1, BC(WB[1][0]), acc[0]);
      acc[0] = MFMA16(a1, BC(WB[1][1]), acc[0]);
      acc[1] = MFMA16(a1, BC(WB[1][2]), acc[1]);
      acc[1] = MFMA16(a1, BC(WB[1][3]), acc[1]);
    }

    // ---- adaptive sampling delay: give producers their window ----
    for (int d = delay; d > 0; --d) __builtin_amdgcn_s_sleep(1);

    // ---- sample h: issue 8 h loads + next-token load ----
    u32x4 HA[8];
    ISSUEJ(0); ISSUEJ(1); ISSUEJ(2); ISSUEJ(3);
    int tok;
    asm volatile("global_load_dword %0, %1, off"
                 : "=v"(tok) : "v"(xin + brow * 512 + ((t + 1) & 511)));
    __builtin_amdgcn_sched_barrier(0);

    // ---- counted tagged consume: queue [ST4,H8,tok]; chunk j at vmcnt(7-2j)
    u32 pend = 0;
    WAITV(7); if (TAGOK(0)) { CONSJ(0); } else pend |= 1u;
    WAITV(5); if (TAGOK(1)) { CONSJ(1); } else pend |= 2u;
    WAITV(3); if (TAGOK(2)) { CONSJ(2); } else pend |= 4u;
    WAITV(1); if (TAGOK(3)) { CONSJ(3); } else pend |= 8u;

    // adaptive update: miss -> +8 (cap 64); hit -> -1 (floor 0)
    delay = pend ? ((delay > 56) ? 64 : delay + 8) : ((delay > 0) ? delay - 1 : 0);

    int fuse = 0;
    while (pend) {           // backoff re-poll; fuse = loud failure, no hang
      __builtin_amdgcn_s_sleep(1);
      RISS(0); RISS(1); RISS(2); RISS(3);
      WAITV(0);
      RCON(0); RCON(1); RCON(2); RCON(3);
      if (++fuse > 16384) break;
    }
    // tok is ready now; bind its reg through the wait so no use is hoisted
    asm volatile("s_waitcnt vmcnt(0)" : "+v"(tok) :: "memory");
    __builtin_amdgcn_sched_barrier(0);

    // ---- cross-wave K-reduction (double-buffered; barrier vmcnt(0) is free)
    red[t & 1][wv][0][lane] = acc[0];
    red[t & 1][wv][1][lane] = acc[1];
    __syncthreads();

    // ---- EA reissue for t+1 (AFTER barrier: no drain stall) ----
    {
      const float* eb = emb + (size_t)(u32)tok * 256;
      LOADP(EA[0], eb + koA); LOADP(EA[1], eb + koA + 4);
      LOADP(EA[2], eb + koB); LOADP(EA[3], eb + koB + 4);
    }

    f32x4 fin0 = red[t & 1][0][0][lane] + red[t & 1][1][0][lane]
               + red[t & 1][2][0][lane] + red[t & 1][3][0][lane];
    f32x4 fin1 = red[t & 1][0][1][lane] + red[t & 1][1][1][lane]
               + red[t & 1][2][1][lane] + red[t & 1][3][1][lane];
    fin0 += bias[0];
    fin1 += bias[1];

    // ---- gates: cols [i(0..7) f(8..15)] in fin0, [g(0..7) o(8..15)] in fin1
    const u32 tagn = (u32)(((t + 1) >> 1) & 1);
#pragma unroll
    for (int r = 0; r < 4; ++r) {
      float iv = fin0[r];
      float gv = fin1[r];
      float fv = __shfl_xor(iv, 8, 64);
      float ov = __shfl_xor(gv, 8, 64);
      float ii = sigm(iv);
      float ff = sigm(fv);
      float gg = tanhf_fast(gv);
      float oo = sigm(ov);
      float cn = ff * cst[r] + ii * gg;
      cst[r] = cn;
      float hnv = oo * tanhf_fast(cn);
      // wave wv stores rows 4*wv+r (gq==wv lanes): 4-way parallel store issue
      if (gq == wv && cl < 8) {
        int row = 4 * gq + r;
        int jj = wg * 8 + cl;
        if (t < 511) {
          u16 hi = bf_hi(hnv);
          u16 lo = bf_hi(hnv - bf_up(hi));
          u32 word = ((u32)hi << 16) | ((u32)lo & 0xfffeu) | tagn;
          STORED(hn + row * 512 + jj, word);
        } else {
          int b = g * 16 + row;
          dout[320 + b * 512 + jj] = hnv;            // h_t
          dout[320 + 32768 + b * 512 + jj] = cn;     // c_t
        }
      }
    }
  }
}

// ---------------- final projection: out = h_T @ W_out^T + b_out --------------
__global__ void k_out(const float* __restrict__ Wout, const float* __restrict__ bout,
                      float* __restrict__ dout) {
  int i = threadIdx.x;
  if (i >= 320) return;
  int b = i / 5, o = i - b * 5;
  const float* hp = dout + 320 + b * 512;
  const float* wp = Wout + (size_t)o * 512;
  float s = 0.f;
#pragma unroll 4
  for (int k = 0; k < 512; k += 4) {
    s += hp[k] * wp[k] + hp[k + 1] * wp[k + 1] + hp[k + 2] * wp[k + 2] + hp[k + 3] * wp[k + 3];
  }
  dout[i] = s + bout[o];
}

extern "C" void kernel_launch(void* const* d_in, const int* in_sizes, int n_in,
                              void* d_out, int out_size, void* d_ws, size_t ws_size,
                              hipStream_t stream) {
  const int* x = (const int*)d_in[0];
  const float* emb = (const float*)d_in[1];
  const float* Wih = (const float*)d_in[2];
  const float* bih = (const float*)d_in[3];
  const float* Whh = (const float*)d_in[4];
  const float* bhh = (const float*)d_in[5];
  const float* Wout = (const float*)d_in[6];
  const float* bout = (const float*)d_in[7];
  float* out = (float*)d_out;
  uint8_t* ws = (uint8_t*)d_ws;

  hipLaunchKernelGGL(k_init, dim3(256), dim3(256), 0, stream, (u32*)ws);
  hipLaunchKernelGGL(k_prep, dim3(768), dim3(256), 0, stream, Wih, Whh, (u16*)(ws + OFF_WF));
  hipLaunchKernelGGL(k_lstm, dim3(256), dim3(256), 0, stream, x, emb, bih, bhh, ws, out);
  hipLaunchKernelGGL(k_out, dim3(1), dim3(320), 0, stream, Wout, bout, out);
}